// Round 9
// baseline (162.454 us; speedup 1.0000x reference)
//
#include <hip/hip_runtime.h>

#define NTOK 8192
#define NCH  256
#define TT   64          // tokens per tile
#define XTP  264         // stride (u16) for [tok][ch] LDS tiles (16B-aligned rows)
#define EKP  72          // stride (u16) for [ch][tok] LDS tiles (16B-aligned rows)

typedef unsigned short u16;
typedef __attribute__((ext_vector_type(8))) short bf16x8;   // MFMA A/B frag (4 VGPR)
typedef __attribute__((ext_vector_type(4))) float f32x4;    // MFMA C/D frag
typedef __attribute__((ext_vector_type(8))) unsigned short u16x8;
typedef __attribute__((ext_vector_type(4))) unsigned short u16x4;

__device__ __forceinline__ float b2f(u16 h){
  union{unsigned u; float f;} x; x.u = ((unsigned)h) << 16; return x.f;
}
__device__ __forceinline__ u16 f2b(float f){
  union{float f; unsigned u;} x; x.f = f;
  unsigned u = x.u;
  return (u16)((u + 0x7FFFu + ((u >> 16) & 1u)) >> 16);   // RNE
}
__device__ __forceinline__ f32x4 mfma16(bf16x8 a, bf16x8 b, f32x4 c){
  return __builtin_amdgcn_mfma_f32_16x16x32_bf16(a, b, c, 0, 0, 0);
}

// ---------------------------------------------------------------------------
// stage_xtile: global fp32 x tile [256 ch][64 tok] -> bf16 LDS dst [tok][XTP]
// via scratch [ch][EKP]. 512 threads. One internal barrier; caller MUST
// __syncthreads() after return before reading dst or overwriting scratch.
// (verified rounds 1/3/7)
// ---------------------------------------------------------------------------
__device__ __forceinline__ void stage_xtile(const float* __restrict__ xb,
                                            u16* scratch, u16* dst, int t)
{
  #pragma unroll
  for (int i = 0; i < 4; ++i) {
    int ch = i * 64 + (t >> 3);          // 64 ch rows per iteration
    int tk = (t & 7) * 8;                // 8 consecutive tokens
    const float* p = xb + (size_t)ch * NTOK + tk;
    float4 v0 = *(const float4*)p;
    float4 v1 = *(const float4*)(p + 4);
    u16x8 pk;
    pk[0]=f2b(v0.x); pk[1]=f2b(v0.y); pk[2]=f2b(v0.z); pk[3]=f2b(v0.w);
    pk[4]=f2b(v1.x); pk[5]=f2b(v1.y); pk[6]=f2b(v1.z); pk[7]=f2b(v1.w);
    *(u16x8*)&scratch[ch * EKP + tk] = pk;
  }
  __syncthreads();
  // transpose: scratch[ch][tok] -> dst[tok][ch]
  #pragma unroll
  for (int p = 0; p < 4; ++p) {
    int idx = p * 512 + t;
    int tok = idx & 63;
    int ch = (idx >> 6) * 8;
    u16x8 o;
    #pragma unroll
    for (int j = 0; j < 8; ++j) o[j] = scratch[(ch + j) * EKP + tok];
    *(u16x8*)&dst[tok * XTP + ch] = o;
  }
}

// ---------------------------------------------------------------------------
// k_prep: convert Wk/Wq/Wv/Wr fp32 -> bf16 row-major into wbf (64 blocks).
// ---------------------------------------------------------------------------
__global__ __launch_bounds__(256)
void k_prep(const float* __restrict__ Wk, const float* __restrict__ Wq,
            const float* __restrict__ Wv, const float* __restrict__ Wr,
            u16* __restrict__ wbf)
{
  const int t = threadIdx.x, bid = blockIdx.x;
  const int mat = bid >> 4;
  const float* src = (mat == 0) ? Wk : (mat == 1) ? Wq : (mat == 2) ? Wv : Wr;
  u16* dst = wbf + mat * 65536;
  const int base = (bid & 15) * 4096 + t * 16;
  #pragma unroll
  for (int i = 0; i < 4; ++i) {
    float4 v = *(const float4*)(src + base + i * 4);
    u16x4 pk; pk[0]=f2b(v.x); pk[1]=f2b(v.y); pk[2]=f2b(v.z); pk[3]=f2b(v.w);
    *(u16x4*)(dst + base + i * 4) = pk;
  }
}

// ---------------------------------------------------------------------------
// k_ctx: 512 threads, 8 waves; wave w owns out-ch slab [32w, 32w+32) == head w.
// In-LDS x stage; INTERLEAVED K+Q GEMM (shared B-operand loads, two
// independent MFMA chains); K->exp->ekb; Q->exp->head-softmax->qnG global;
// V-GEMM->vt (aliased over x tile); ctx GEMM per head + denom row-sums ->
// streaming bf16/fp32 partial stores.
// ---------------------------------------------------------------------------
__global__ __launch_bounds__(512, 4)
void k_ctx(const float* __restrict__ x, const u16* __restrict__ wbf,
           const float* __restrict__ bk, const float* __restrict__ bq,
           const float* __restrict__ bv,
           u16* __restrict__ qnG,
           u16* __restrict__ ctxPart, float* __restrict__ denomPart)
{
  __shared__ u16 bufA[NCH * EKP];   // stage: x tile [64][XTP]; later vt [256][EKP]
  __shared__ u16 ekb[NCH * EKP];    // stage scratch [ch][tok]; later exp(K) [ch][tok]

  const int t = threadIdx.x;
  const int b = blockIdx.x >> 7, g = blockIdx.x & 127;
  const int w = t >> 6, lane = t & 63;
  const int l15 = lane & 15, quad = lane >> 4;
  const u16* Wkb = wbf;
  const u16* Wqb = wbf + 65536;
  const u16* Wvb = wbf + 2 * 65536;

  stage_xtile(x + (size_t)b * NCH * NTOK + g * TT, ekb, bufA, t);
  __syncthreads();   // bufA ready; all ekb scratch reads done

  // ---- INTERLEAVED K+Q GEMM: shared bx loads, 2 independent MFMA chains ----
  f32x4 acck[2][4], accq[2][4];
  #pragma unroll
  for (int mi = 0; mi < 2; ++mi)
    #pragma unroll
    for (int nj = 0; nj < 4; ++nj) { acck[mi][nj] = (f32x4)0.f; accq[mi][nj] = (f32x4)0.f; }
  for (int k0 = 0; k0 < NCH; k0 += 32) {
    bf16x8 ak[2], aq[2], bx[4];
    #pragma unroll
    for (int mi = 0; mi < 2; ++mi) {
      ak[mi] = *(const bf16x8*)(Wkb + (size_t)(w * 32 + mi * 16 + l15) * NCH + k0 + quad * 8);
      aq[mi] = *(const bf16x8*)(Wqb + (size_t)(w * 32 + mi * 16 + l15) * NCH + k0 + quad * 8);
    }
    #pragma unroll
    for (int nj = 0; nj < 4; ++nj)
      bx[nj] = *(const bf16x8*)&bufA[(nj * 16 + l15) * XTP + k0 + quad * 8];
    #pragma unroll
    for (int mi = 0; mi < 2; ++mi)
      #pragma unroll
      for (int nj = 0; nj < 4; ++nj) {
        acck[mi][nj] = mfma16(ak[mi], bx[nj], acck[mi][nj]);
        accq[mi][nj] = mfma16(aq[mi], bx[nj], accq[mi][nj]);
      }
  }

  // K epilogue: bias + exp -> ekb [ch][tok] (wave-exclusive rows)
  #pragma unroll
  for (int mi = 0; mi < 2; ++mi) {
    float4 bb = *(const float4*)(bk + w * 32 + mi * 16 + quad * 4);
    #pragma unroll
    for (int nj = 0; nj < 4; ++nj) {
      int tok = nj * 16 + l15, chb = w * 32 + mi * 16 + quad * 4;
      ekb[(chb + 0) * EKP + tok] = f2b(__expf(acck[mi][nj][0] + bb.x));
      ekb[(chb + 1) * EKP + tok] = f2b(__expf(acck[mi][nj][1] + bb.y));
      ekb[(chb + 2) * EKP + tok] = f2b(__expf(acck[mi][nj][2] + bb.z));
      ekb[(chb + 3) * EKP + tok] = f2b(__expf(acck[mi][nj][3] + bb.w));
    }
  }

  // Q epilogue: bias + exp; per-(head,token) softmax inv via quad shfl;
  // write qn = e*inv (bf16) to global qnG tile [tok][ch] (rdenom deferred).
  {
    #pragma unroll
    for (int mi = 0; mi < 2; ++mi) {
      float4 bb = *(const float4*)(bq + w * 32 + mi * 16 + quad * 4);
      #pragma unroll
      for (int nj = 0; nj < 4; ++nj) {
        accq[mi][nj][0] = __expf(accq[mi][nj][0] + bb.x);
        accq[mi][nj][1] = __expf(accq[mi][nj][1] + bb.y);
        accq[mi][nj][2] = __expf(accq[mi][nj][2] + bb.z);
        accq[mi][nj][3] = __expf(accq[mi][nj][3] + bb.w);
      }
    }
    float inv[4];
    #pragma unroll
    for (int nj = 0; nj < 4; ++nj) {
      float s = 0.f;
      #pragma unroll
      for (int mi = 0; mi < 2; ++mi)
        #pragma unroll
        for (int r = 0; r < 4; ++r) s += accq[mi][nj][r];
      s += __shfl_xor(s, 16);
      s += __shfl_xor(s, 32);
      inv[nj] = 1.0f / s;
    }
    u16* qdst = qnG + ((size_t)(b * 128 + g) << 14);
    #pragma unroll
    for (int mi = 0; mi < 2; ++mi)
      #pragma unroll
      for (int nj = 0; nj < 4; ++nj) {
        u16x4 pk;
        pk[0] = f2b(accq[mi][nj][0] * inv[nj]);
        pk[1] = f2b(accq[mi][nj][1] * inv[nj]);
        pk[2] = f2b(accq[mi][nj][2] * inv[nj]);
        pk[3] = f2b(accq[mi][nj][3] * inv[nj]);
        *(u16x4*)(qdst + ((nj * 16 + l15) << 8) + w * 32 + mi * 16 + quad * 4) = pk;
      }
  }

  // ---- V GEMM (reuses acck regs) ----
  #pragma unroll
  for (int mi = 0; mi < 2; ++mi)
    #pragma unroll
    for (int nj = 0; nj < 4; ++nj) acck[mi][nj] = (f32x4)0.f;
  for (int k0 = 0; k0 < NCH; k0 += 32) {
    bf16x8 af[2], bx[4];
    #pragma unroll
    for (int mi = 0; mi < 2; ++mi)
      af[mi] = *(const bf16x8*)(Wvb + (size_t)(w * 32 + mi * 16 + l15) * NCH + k0 + quad * 8);
    #pragma unroll
    for (int nj = 0; nj < 4; ++nj)
      bx[nj] = *(const bf16x8*)&bufA[(nj * 16 + l15) * XTP + k0 + quad * 8];
    #pragma unroll
    for (int mi = 0; mi < 2; ++mi)
      #pragma unroll
      for (int nj = 0; nj < 4; ++nj) acck[mi][nj] = mfma16(af[mi], bx[nj], acck[mi][nj]);
  }
  __syncthreads();   // all waves done reading x tile; safe to overwrite with vt
  #pragma unroll
  for (int mi = 0; mi < 2; ++mi) {
    float4 bb = *(const float4*)(bv + w * 32 + mi * 16 + quad * 4);
    #pragma unroll
    for (int nj = 0; nj < 4; ++nj) {
      int tok = nj * 16 + l15, chb = w * 32 + mi * 16 + quad * 4;
      bufA[(chb + 0) * EKP + tok] = f2b(acck[mi][nj][0] + bb.x);
      bufA[(chb + 1) * EKP + tok] = f2b(acck[mi][nj][1] + bb.y);
      bufA[(chb + 2) * EKP + tok] = f2b(acck[mi][nj][2] + bb.z);
      bufA[(chb + 3) * EKP + tok] = f2b(acck[mi][nj][3] + bb.w);
    }
  }
  __syncthreads();

  // ---- ctx GEMM: wave w -> head w. D[kk][vch] = sum_s ek*v ----
  f32x4 cacc[2][2];
  #pragma unroll
  for (int mi = 0; mi < 2; ++mi)
    #pragma unroll
    for (int nj = 0; nj < 2; ++nj) cacc[mi][nj] = (f32x4)0.f;
  #pragma unroll
  for (int kc = 0; kc < 2; ++kc) {
    bf16x8 ae[2], bvv[2];
    #pragma unroll
    for (int mi = 0; mi < 2; ++mi)
      ae[mi] = *(const bf16x8*)&ekb[(w * 32 + mi * 16 + l15) * EKP + kc * 32 + quad * 8];
    #pragma unroll
    for (int nj = 0; nj < 2; ++nj)
      bvv[nj] = *(const bf16x8*)&bufA[(w * 32 + nj * 16 + l15) * EKP + kc * 32 + quad * 8];
    #pragma unroll
    for (int mi = 0; mi < 2; ++mi)
      #pragma unroll
      for (int nj = 0; nj < 2; ++nj)
        cacc[mi][nj] = mfma16(ae[mi], bvv[nj], cacc[mi][nj]);
  }
  // denominator: threads 0..255 each sum one ek row over 64 tokens
  float dsum = 0.f;
  if (t < 256) {
    #pragma unroll
    for (int s = 0; s < TT; s += 8) {
      u16x8 v = *(const u16x8*)&ekb[t * EKP + s];
      #pragma unroll
      for (int j = 0; j < 8; ++j) dsum += b2f(v[j]);
    }
  }

  // ---- streaming partial stores (bf16 ctx + fp32 denom, no contention) ----
  u16* cp = ctxPart + ((size_t)(b * 128 + g) << 13);
  #pragma unroll
  for (int mi = 0; mi < 2; ++mi)
    #pragma unroll
    for (int nj = 0; nj < 2; ++nj)
      #pragma unroll
      for (int r = 0; r < 4; ++r) {
        int e = ((w * 32 + mi * 16 + quad * 4 + r) << 5) + nj * 16 + l15;
        cp[e] = f2b(cacc[mi][nj][r]);
      }
  if (t < 256)
    denomPart[(size_t)(b * 128 + g) * 256 + t] = dsum;
}

// ---------------------------------------------------------------------------
// k_red: sum 128 partials -> ctxT bf16 [b][h][vch][kk] (A-operand-ready) and
// rdenomF = 1/denom fp32 [b][256]  (verified rounds 0/3/7)
// ---------------------------------------------------------------------------
__global__ __launch_bounds__(256)
void k_red(const u16* __restrict__ ctxPart, const float* __restrict__ denomPart,
           u16* __restrict__ ctxT, float* __restrict__ rdenomF)
{
  int i = blockIdx.x * 256 + threadIdx.x;
  if (i < 32768) {
    int b = i >> 13, e = i & 8191;
    const u16* p = ctxPart + ((size_t)(b * 128) << 13) + e;
    float s0 = 0.f, s1 = 0.f, s2 = 0.f, s3 = 0.f;
    #pragma unroll 8
    for (int g = 0; g < 128; g += 4) {
      s0 += b2f(p[(size_t)(g + 0) << 13]);
      s1 += b2f(p[(size_t)(g + 1) << 13]);
      s2 += b2f(p[(size_t)(g + 2) << 13]);
      s3 += b2f(p[(size_t)(g + 3) << 13]);
    }
    float s = (s0 + s1) + (s2 + s3);
    int hh = e >> 10, kk = (e >> 5) & 31, vch = e & 31;
    ctxT[(((b * 8 + hh) * 32 + vch) << 5) + kk] = f2b(s);
  } else if (i < 33792) {
    int j = i - 32768, b = j >> 8, ch = j & 255;
    const float* p = denomPart + (size_t)(b * 128) * 256 + ch;
    float s = 0.f;
    #pragma unroll 8
    for (int g = 0; g < 128; ++g) s += p[(size_t)g << 8];
    rdenomF[j] = 1.0f / s;
  }
}

// ---------------------------------------------------------------------------
// k_out: 512 threads, 8 waves; wave w owns head w / out-ch slab [32w,32w+32).
// Load qn tile (single coalesced pass) -> qs; PREFETCH all Wr A-frags into
// regs (latency hidden under stage/att); ac = ctxT * rdenom; att GEMM (out
// aliased over qs, wave-exclusive cols); Wr-GEMM (reg A-operand); +bias +
// fp32 residual (early loads); coalesced float4 store.
// ---------------------------------------------------------------------------
__global__ __launch_bounds__(512, 4)
void k_out(const float* __restrict__ x, const u16* __restrict__ wbf,
           const float* __restrict__ br,
           const u16* __restrict__ ctxT, const float* __restrict__ rdenomF,
           const u16* __restrict__ qnG, float* __restrict__ out)
{
  __shared__ u16 qs[TT * XTP];      // qn [tok][ch], then att (wave-exclusive cols)

  const int t = threadIdx.x;
  const int b = blockIdx.x >> 7, g = blockIdx.x & 127;
  const int w = t >> 6, lane = t & 63;
  const int l15 = lane & 15, quad = lane >> 4;
  const u16* Wrb = wbf + 3 * 65536;

  // ---- stage qn tile (32 KB contiguous, coalesced 16B; single pass) ----
  {
    const u16* src = qnG + ((size_t)(b * 128 + g) << 14);
    #pragma unroll
    for (int i = 0; i < 4; ++i) {
      int f = i * 4096 + t * 8;
      int tok = f >> 8, ch = f & 255;
      *(u16x8*)&qs[tok * XTP + ch] = *(const u16x8*)(src + f);
    }
  }

  // ---- prefetch all Wr A-frags (16 x bf16x8 = 64 VGPR; L2-hot; latency
  //      hides under qn stage + att phase) ----
  bf16x8 wr[8][2];
  #pragma unroll
  for (int k = 0; k < 8; ++k)
    #pragma unroll
    for (int mi = 0; mi < 2; ++mi)
      wr[k][mi] = *(const bf16x8*)(Wrb + (size_t)(w * 32 + mi * 16 + l15) * NCH + k * 32 + quad * 8);

  // ---- early residual loads (fp32 x, 64B-coalesced per 16-lane group,
  //      L3-warm; consumed only at the final store) ----
  float resv[2][4][4];
  {
    const float* xr = x + (size_t)b * NCH * NTOK + g * TT;
    #pragma unroll
    for (int mi = 0; mi < 2; ++mi)
      #pragma unroll
      for (int nj = 0; nj < 4; ++nj)
        #pragma unroll
        for (int r = 0; r < 4; ++r)
          resv[mi][nj][r] = xr[(size_t)(w * 32 + mi * 16 + quad * 4 + r) * NTOK + nj * 16 + l15];
  }

  // ---- ctx A-frags scaled by rdenom (kk = reduction dim of att GEMM) ----
  bf16x8 ac[2];
  {
    float4 r0 = *(const float4*)(rdenomF + b * 256 + w * 32 + quad * 8);
    float4 r1 = *(const float4*)(rdenomF + b * 256 + w * 32 + quad * 8 + 4);
    float rd[8] = {r0.x, r0.y, r0.z, r0.w, r1.x, r1.y, r1.z, r1.w};
    #pragma unroll
    for (int mi = 0; mi < 2; ++mi) {
      bf16x8 c = *(const bf16x8*)(ctxT + (((size_t)(b * 8 + w) * 32 + mi * 16 + l15) << 5) + quad * 8);
      #pragma unroll
      for (int j = 0; j < 8; ++j)
        ac[mi][j] = (short)f2b(b2f((u16)c[j]) * rd[j]);
    }
  }
  __syncthreads();   // qs ready

  // ---- att GEMM: wave w -> head w; D[vch][tok]; K=32 (one step) ----
  f32x4 aacc[2][4];
  {
    #pragma unroll
    for (int nj = 0; nj < 4; ++nj) {
      bf16x8 bqf = *(const bf16x8*)&qs[(nj * 16 + l15) * XTP + w * 32 + quad * 8];
      #pragma unroll
      for (int mi = 0; mi < 2; ++mi)
        aacc[mi][nj] = mfma16(ac[mi], bqf, (f32x4)0.f);
    }
  }
  // write att over qs (each wave writes exactly the columns only it read)
  #pragma unroll
  for (int mi = 0; mi < 2; ++mi)
    #pragma unroll
    for (int nj = 0; nj < 4; ++nj) {
      u16x4 pk;
      pk[0] = f2b(aacc[mi][nj][0]);
      pk[1] = f2b(aacc[mi][nj][1]);
      pk[2] = f2b(aacc[mi][nj][2]);
      pk[3] = f2b(aacc[mi][nj][3]);
      *(u16x4*)&qs[(nj * 16 + l15) * XTP + w * 32 + mi * 16 + quad * 4] = pk;
    }
  __syncthreads();

  // ---- Wr GEMM (A-operand already in registers) ----
  f32x4 acc[2][4];
  #pragma unroll
  for (int mi = 0; mi < 2; ++mi)
    #pragma unroll
    for (int nj = 0; nj < 4; ++nj) acc[mi][nj] = (f32x4)0.f;
  #pragma unroll
  for (int k = 0; k < 8; ++k) {
    bf16x8 bx[4];
    #pragma unroll
    for (int nj = 0; nj < 4; ++nj)
      bx[nj] = *(const bf16x8*)&qs[(nj * 16 + l15) * XTP + k * 32 + quad * 8];
    #pragma unroll
    for (int mi = 0; mi < 2; ++mi)
      #pragma unroll
      for (int nj = 0; nj < 4; ++nj) acc[mi][nj] = mfma16(wr[k][mi], bx[nj], acc[mi][nj]);
  }
  // bias + fp32 residual + transposed float4 store
  #pragma unroll
  for (int mi = 0; mi < 2; ++mi) {
    float4 bb = *(const float4*)(br + w * 32 + mi * 16 + quad * 4);
    #pragma unroll
    for (int nj = 0; nj < 4; ++nj) {
      int tok = nj * 16 + l15;
      float4 o;
      o.x = acc[mi][nj][0] + bb.x + resv[mi][nj][0];
      o.y = acc[mi][nj][1] + bb.y + resv[mi][nj][1];
      o.z = acc[mi][nj][2] + bb.z + resv[mi][nj][2];
      o.w = acc[mi][nj][3] + bb.w + resv[mi][nj][3];
      *(float4*)(out + (((size_t)(b * NTOK + g * TT + tok)) << 8) + w * 32 + mi * 16 + quad * 4) = o;
    }
  }
}

extern "C" void kernel_launch(void* const* d_in, const int* in_sizes, int n_in,
                              void* d_out, int out_size, void* d_ws, size_t ws_size,
                              hipStream_t stream) {
  const float* x  = (const float*)d_in[0];
  const float* Wk = (const float*)d_in[1];
  const float* bk = (const float*)d_in[2];
  const float* Wq = (const float*)d_in[3];
  const float* bq = (const float*)d_in[4];
  const float* Wv = (const float*)d_in[5];
  const float* bv = (const float*)d_in[6];
  const float* Wr = (const float*)d_in[7];
  const float* br = (const float*)d_in[8];
  float* out = (float*)d_out;

  // ws layout (~25.5 MB total)
  char* wsb = (char*)d_ws;
  u16*   ctxPart   = (u16*)wsb;                         // 512*8192 u16  = 8 MB
  float* denomPart = (float*)(wsb + 8388608);           // 512*256 f32   = 0.5 MB
  u16*   ctxT      = (u16*)(wsb + 8912896);             // 32768 u16     = 64 KB
  float* rdenomF   = (float*)(wsb + 8978432);           // 1024 f32      = 4 KB
  u16*   wbf       = (u16*)(wsb + 8982528);             // 4*65536 u16   = 0.5 MB
  u16*   qnG       = (u16*)(wsb + 9506816);             // 4*8192*256 u16= 16 MB

  hipLaunchKernelGGL(k_prep, dim3(64), dim3(256), 0, stream,
                     Wk, Wq, Wv, Wr, wbf);
  hipLaunchKernelGGL(k_ctx, dim3(512), dim3(512), 0, stream,
                     x, wbf, bk, bq, bv, qnG, ctxPart, denomPart);
  hipLaunchKernelGGL(k_red, dim3(132), dim3(256), 0, stream,
                     ctxPart, denomPart, ctxT, rdenomF);
  hipLaunchKernelGGL(k_out, dim3(512), dim3(512), 0, stream,
                     x, wbf, br, ctxT, rdenomF, qnG, out);
}

// Round 10
// 146.271 us; speedup vs baseline: 1.1106x; 1.1106x over previous
//
#include <hip/hip_runtime.h>
#include <hip/hip_bf16.h>

#define NTOK 8192
#define NCH  256
#define TT   64          // tokens per tile
#define XTP  264         // stride (u16) for [tok][ch] LDS tiles (16B-aligned rows)
#define EKP  72          // stride (u16) for [ch][tok] LDS tiles (16B-aligned rows)

typedef unsigned short u16;
typedef __attribute__((ext_vector_type(8))) short bf16x8;   // MFMA A/B frag (4 VGPR)
typedef __attribute__((ext_vector_type(4))) float f32x4;    // MFMA C/D frag
typedef __attribute__((ext_vector_type(8))) unsigned short u16x8;
typedef __attribute__((ext_vector_type(4))) unsigned short u16x4;

// Hardware bf16 conversions (v_cvt path; RNE) — replaces manual bit-twiddled
// RNE (~4-5 VALU ops/elem) that dominated VALUBusy in rounds 1-9.
__device__ __forceinline__ float b2f(u16 v){
  union { u16 u; __hip_bfloat16 h; } c; c.u = v; return __bfloat162float(c.h);
}
__device__ __forceinline__ u16 f2b(float f){
  union { __hip_bfloat16 h; u16 u; } c; c.h = __float2bfloat16(f); return c.u;
}
__device__ __forceinline__ f32x4 mfma16(bf16x8 a, bf16x8 b, f32x4 c){
  return __builtin_amdgcn_mfma_f32_16x16x32_bf16(a, b, c, 0, 0, 0);
}

// ---------------------------------------------------------------------------
// stage_xtile: global fp32 x tile [256 ch][64 tok] -> bf16 LDS dst [tok][XTP]
// via scratch [ch][EKP]. 512 threads. One internal barrier; caller MUST
// __syncthreads() after return before reading dst or overwriting scratch.
// (structure verified rounds 1/3)
// ---------------------------------------------------------------------------
__device__ __forceinline__ void stage_xtile(const float* __restrict__ xb,
                                            u16* scratch, u16* dst, int t)
{
  #pragma unroll
  for (int i = 0; i < 4; ++i) {
    int ch = i * 64 + (t >> 3);          // 64 ch rows per iteration
    int tk = (t & 7) * 8;                // 8 consecutive tokens
    const float* p = xb + (size_t)ch * NTOK + tk;
    float4 v0 = *(const float4*)p;
    float4 v1 = *(const float4*)(p + 4);
    u16x8 pk;
    pk[0]=f2b(v0.x); pk[1]=f2b(v0.y); pk[2]=f2b(v0.z); pk[3]=f2b(v0.w);
    pk[4]=f2b(v1.x); pk[5]=f2b(v1.y); pk[6]=f2b(v1.z); pk[7]=f2b(v1.w);
    *(u16x8*)&scratch[ch * EKP + tk] = pk;
  }
  __syncthreads();
  // transpose: scratch[ch][tok] -> dst[tok][ch]
  #pragma unroll
  for (int p = 0; p < 4; ++p) {
    int idx = p * 512 + t;
    int tok = idx & 63;
    int ch = (idx >> 6) * 8;
    u16x8 o;
    #pragma unroll
    for (int j = 0; j < 8; ++j) o[j] = scratch[(ch + j) * EKP + tok];
    *(u16x8*)&dst[tok * XTP + ch] = o;
  }
}

// ---------------------------------------------------------------------------
// k_prep: convert Wk/Wq/Wv/Wr fp32 -> bf16 row-major into wbf (64 blocks).
// ---------------------------------------------------------------------------
__global__ __launch_bounds__(256)
void k_prep(const float* __restrict__ Wk, const float* __restrict__ Wq,
            const float* __restrict__ Wv, const float* __restrict__ Wr,
            u16* __restrict__ wbf)
{
  const int t = threadIdx.x, bid = blockIdx.x;
  const int mat = bid >> 4;
  const float* src = (mat == 0) ? Wk : (mat == 1) ? Wq : (mat == 2) ? Wv : Wr;
  u16* dst = wbf + mat * 65536;
  const int base = (bid & 15) * 4096 + t * 16;
  #pragma unroll
  for (int i = 0; i < 4; ++i) {
    float4 v = *(const float4*)(src + base + i * 4);
    u16x4 pk; pk[0]=f2b(v.x); pk[1]=f2b(v.y); pk[2]=f2b(v.z); pk[3]=f2b(v.w);
    *(u16x4*)(dst + base + i * 4) = pk;
  }
}

// ---------------------------------------------------------------------------
// k_ctx: 512 threads, 8 waves; wave w owns out-ch slab [32w, 32w+32) == head w.
// In-LDS x stage; K-GEMM(MFMA)->exp->ekb; V-GEMM->vt (aliased over x tile);
// ctx GEMM per head + denom row-sums -> streaming bf16/fp32 partial stores.
// (structure = round 3, verified 144.9us)
// ---------------------------------------------------------------------------
__global__ __launch_bounds__(512, 4)
void k_ctx(const float* __restrict__ x, const u16* __restrict__ wbf,
           const float* __restrict__ bk, const float* __restrict__ bv,
           u16* __restrict__ ctxPart, float* __restrict__ denomPart)
{
  __shared__ u16 bufA[NCH * EKP];   // stage: x tile [64][XTP]; later vt [256][EKP]
  __shared__ u16 ekb[NCH * EKP];    // stage scratch [ch][tok]; later exp(K) [ch][tok]

  const int t = threadIdx.x;
  const int b = blockIdx.x >> 7, g = blockIdx.x & 127;
  const int w = t >> 6, lane = t & 63;
  const int l15 = lane & 15, quad = lane >> 4;
  const u16* Wkb = wbf;
  const u16* Wvb = wbf + 2 * 65536;

  stage_xtile(x + (size_t)b * NCH * NTOK + g * TT, ekb, bufA, t);
  __syncthreads();   // bufA ready; all ekb scratch reads done

  f32x4 acc[2][4];

  // ---- K GEMM: D[och][tok], wave w owns och [32w, 32w+32) ----
  #pragma unroll
  for (int mi = 0; mi < 2; ++mi)
    #pragma unroll
    for (int nj = 0; nj < 4; ++nj) acc[mi][nj] = (f32x4)0.f;
  for (int k0 = 0; k0 < NCH; k0 += 32) {
    bf16x8 af[2], bx[4];
    #pragma unroll
    for (int mi = 0; mi < 2; ++mi)
      af[mi] = *(const bf16x8*)(Wkb + (size_t)(w * 32 + mi * 16 + l15) * NCH + k0 + quad * 8);
    #pragma unroll
    for (int nj = 0; nj < 4; ++nj)
      bx[nj] = *(const bf16x8*)&bufA[(nj * 16 + l15) * XTP + k0 + quad * 8];
    #pragma unroll
    for (int mi = 0; mi < 2; ++mi)
      #pragma unroll
      for (int nj = 0; nj < 4; ++nj) acc[mi][nj] = mfma16(af[mi], bx[nj], acc[mi][nj]);
  }
  // epilogue: bias + exp -> ekb [ch][tok] (wave-exclusive rows)
  #pragma unroll
  for (int mi = 0; mi < 2; ++mi) {
    float4 bb = *(const float4*)(bk + w * 32 + mi * 16 + quad * 4);
    #pragma unroll
    for (int nj = 0; nj < 4; ++nj) {
      int tok = nj * 16 + l15, chb = w * 32 + mi * 16 + quad * 4;
      ekb[(chb + 0) * EKP + tok] = f2b(__expf(acc[mi][nj][0] + bb.x));
      ekb[(chb + 1) * EKP + tok] = f2b(__expf(acc[mi][nj][1] + bb.y));
      ekb[(chb + 2) * EKP + tok] = f2b(__expf(acc[mi][nj][2] + bb.z));
      ekb[(chb + 3) * EKP + tok] = f2b(__expf(acc[mi][nj][3] + bb.w));
    }
  }

  // ---- V GEMM (re-uses acc regs) ----
  #pragma unroll
  for (int mi = 0; mi < 2; ++mi)
    #pragma unroll
    for (int nj = 0; nj < 4; ++nj) acc[mi][nj] = (f32x4)0.f;
  for (int k0 = 0; k0 < NCH; k0 += 32) {
    bf16x8 af[2], bx[4];
    #pragma unroll
    for (int mi = 0; mi < 2; ++mi)
      af[mi] = *(const bf16x8*)(Wvb + (size_t)(w * 32 + mi * 16 + l15) * NCH + k0 + quad * 8);
    #pragma unroll
    for (int nj = 0; nj < 4; ++nj)
      bx[nj] = *(const bf16x8*)&bufA[(nj * 16 + l15) * XTP + k0 + quad * 8];
    #pragma unroll
    for (int mi = 0; mi < 2; ++mi)
      #pragma unroll
      for (int nj = 0; nj < 4; ++nj) acc[mi][nj] = mfma16(af[mi], bx[nj], acc[mi][nj]);
  }
  __syncthreads();   // all waves done reading x tile; safe to overwrite with vt
  #pragma unroll
  for (int mi = 0; mi < 2; ++mi) {
    float4 bb = *(const float4*)(bv + w * 32 + mi * 16 + quad * 4);
    #pragma unroll
    for (int nj = 0; nj < 4; ++nj) {
      int tok = nj * 16 + l15, chb = w * 32 + mi * 16 + quad * 4;
      bufA[(chb + 0) * EKP + tok] = f2b(acc[mi][nj][0] + bb.x);
      bufA[(chb + 1) * EKP + tok] = f2b(acc[mi][nj][1] + bb.y);
      bufA[(chb + 2) * EKP + tok] = f2b(acc[mi][nj][2] + bb.z);
      bufA[(chb + 3) * EKP + tok] = f2b(acc[mi][nj][3] + bb.w);
    }
  }
  __syncthreads();

  // ---- ctx GEMM: wave w -> head w. D[kk][vch] = sum_s ek*v ----
  f32x4 cacc[2][2];
  #pragma unroll
  for (int mi = 0; mi < 2; ++mi)
    #pragma unroll
    for (int nj = 0; nj < 2; ++nj) cacc[mi][nj] = (f32x4)0.f;
  #pragma unroll
  for (int kc = 0; kc < 2; ++kc) {
    bf16x8 ae[2], bvv[2];
    #pragma unroll
    for (int mi = 0; mi < 2; ++mi)
      ae[mi] = *(const bf16x8*)&ekb[(w * 32 + mi * 16 + l15) * EKP + kc * 32 + quad * 8];
    #pragma unroll
    for (int nj = 0; nj < 2; ++nj)
      bvv[nj] = *(const bf16x8*)&bufA[(w * 32 + nj * 16 + l15) * EKP + kc * 32 + quad * 8];
    #pragma unroll
    for (int mi = 0; mi < 2; ++mi)
      #pragma unroll
      for (int nj = 0; nj < 2; ++nj)
        cacc[mi][nj] = mfma16(ae[mi], bvv[nj], cacc[mi][nj]);
  }
  // denominator: threads 0..255 each sum one ek row over 64 tokens
  float dsum = 0.f;
  if (t < 256) {
    #pragma unroll
    for (int s = 0; s < TT; s += 8) {
      u16x8 v = *(const u16x8*)&ekb[t * EKP + s];
      #pragma unroll
      for (int j = 0; j < 8; ++j) dsum += b2f(v[j]);
    }
  }

  // ---- streaming partial stores (bf16 ctx + fp32 denom, no contention) ----
  u16* cp = ctxPart + ((size_t)(b * 128 + g) << 13);
  #pragma unroll
  for (int mi = 0; mi < 2; ++mi)
    #pragma unroll
    for (int nj = 0; nj < 2; ++nj)
      #pragma unroll
      for (int r = 0; r < 4; ++r) {
        int e = ((w * 32 + mi * 16 + quad * 4 + r) << 5) + nj * 16 + l15;
        cp[e] = f2b(cacc[mi][nj][r]);
      }
  if (t < 256)
    denomPart[(size_t)(b * 128 + g) * 256 + t] = dsum;
}

// ---------------------------------------------------------------------------
// k_red: sum 128 partials -> ctxT bf16 [b][h][vch][kk] (A-operand-ready) and
// rdenomF = 1/denom fp32 [b][256]  (verified rounds 0/3)
// ---------------------------------------------------------------------------
__global__ __launch_bounds__(256)
void k_red(const u16* __restrict__ ctxPart, const float* __restrict__ denomPart,
           u16* __restrict__ ctxT, float* __restrict__ rdenomF)
{
  int i = blockIdx.x * 256 + threadIdx.x;
  if (i < 32768) {
    int b = i >> 13, e = i & 8191;
    const u16* p = ctxPart + ((size_t)(b * 128) << 13) + e;
    float s0 = 0.f, s1 = 0.f, s2 = 0.f, s3 = 0.f;
    #pragma unroll 8
    for (int g = 0; g < 128; g += 4) {
      s0 += b2f(p[(size_t)(g + 0) << 13]);
      s1 += b2f(p[(size_t)(g + 1) << 13]);
      s2 += b2f(p[(size_t)(g + 2) << 13]);
      s3 += b2f(p[(size_t)(g + 3) << 13]);
    }
    float s = (s0 + s1) + (s2 + s3);
    int hh = e >> 10, kk = (e >> 5) & 31, vch = e & 31;
    ctxT[(((b * 8 + hh) * 32 + vch) << 5) + kk] = f2b(s);
  } else if (i < 33792) {
    int j = i - 32768, b = j >> 8, ch = j & 255;
    const float* p = denomPart + (size_t)(b * 128) * 256 + ch;
    float s = 0.f;
    #pragma unroll 8
    for (int g = 0; g < 128; ++g) s += p[(size_t)g << 8];
    rdenomF[j] = 1.0f / s;
  }
}

// ---------------------------------------------------------------------------
// k_out: 512 threads, 8 waves; wave w owns head w / out-ch slab [32w,32w+32).
// In-LDS x stage (L3-hot re-read); Q-GEMM->exp->head softmax * rdenom -> qn
// LDS [tok][ch]; att GEMM (A=ctxT, out aliased over qn, wave-exclusive cols);
// Wr-GEMM; +bias +bf16 residual; coalesced float4 store.
// (structure = round 3, verified 144.9us)
// ---------------------------------------------------------------------------
__global__ __launch_bounds__(512, 4)
void k_out(const float* __restrict__ x, const u16* __restrict__ wbf,
           const float* __restrict__ bq, const float* __restrict__ br,
           const u16* __restrict__ ctxT, const float* __restrict__ rdenomF,
           float* __restrict__ out)
{
  __shared__ u16 xs[TT * XTP];      // x tile [tok][ch]
  __shared__ u16 qs[NCH * EKP];     // stage scratch; then qn/att [tok][XTP]

  const int t = threadIdx.x;
  const int b = blockIdx.x >> 7, g = blockIdx.x & 127;
  const int w = t >> 6, lane = t & 63;
  const int l15 = lane & 15, quad = lane >> 4;
  const u16* Wqb = wbf + 65536;
  const u16* Wrb = wbf + 3 * 65536;

  stage_xtile(x + (size_t)b * NCH * NTOK + g * TT, qs, xs, t);
  __syncthreads();   // xs ready; all qs scratch reads done

  // ---- ctx A-frags from bf16 ctxT (A-operand-ready; L2-hot) ----
  bf16x8 ac[2];
  #pragma unroll
  for (int mi = 0; mi < 2; ++mi)
    ac[mi] = *(const bf16x8*)(ctxT + (((size_t)(b * 8 + w) * 32 + mi * 16 + l15) << 5) + quad * 8);

  f32x4 acc[2][4];
  // ---- Q GEMM: wave w -> och [32w, 32w+32) == head w ----
  #pragma unroll
  for (int mi = 0; mi < 2; ++mi)
    #pragma unroll
    for (int nj = 0; nj < 4; ++nj) acc[mi][nj] = (f32x4)0.f;
  for (int k0 = 0; k0 < NCH; k0 += 32) {
    bf16x8 af[2], bx[4];
    #pragma unroll
    for (int mi = 0; mi < 2; ++mi)
      af[mi] = *(const bf16x8*)(Wqb + (size_t)(w * 32 + mi * 16 + l15) * NCH + k0 + quad * 8);
    #pragma unroll
    for (int nj = 0; nj < 4; ++nj)
      bx[nj] = *(const bf16x8*)&xs[(nj * 16 + l15) * XTP + k0 + quad * 8];
    #pragma unroll
    for (int mi = 0; mi < 2; ++mi)
      #pragma unroll
      for (int nj = 0; nj < 4; ++nj) acc[mi][nj] = mfma16(af[mi], bx[nj], acc[mi][nj]);
  }
  // bias + exp (in place)
  #pragma unroll
  for (int mi = 0; mi < 2; ++mi) {
    float4 bb = *(const float4*)(bq + w * 32 + mi * 16 + quad * 4);
    #pragma unroll
    for (int nj = 0; nj < 4; ++nj) {
      acc[mi][nj][0] = __expf(acc[mi][nj][0] + bb.x);
      acc[mi][nj][1] = __expf(acc[mi][nj][1] + bb.y);
      acc[mi][nj][2] = __expf(acc[mi][nj][2] + bb.z);
      acc[mi][nj][3] = __expf(acc[mi][nj][3] + bb.w);
    }
  }
  // per-(head, token) softmax denom: in-lane sum + quad reduction
  float inv[4];
  #pragma unroll
  for (int nj = 0; nj < 4; ++nj) {
    float s = 0.f;
    #pragma unroll
    for (int mi = 0; mi < 2; ++mi)
      #pragma unroll
      for (int r = 0; r < 4; ++r) s += acc[mi][nj][r];
    s += __shfl_xor(s, 16);
    s += __shfl_xor(s, 32);
    inv[nj] = 1.0f / s;
  }
  // qn = e * inv * rdenom -> qs [tok][ch], packed b64 writes
  #pragma unroll
  for (int mi = 0; mi < 2; ++mi) {
    float4 rd = *(const float4*)(rdenomF + b * 256 + w * 32 + mi * 16 + quad * 4);
    #pragma unroll
    for (int nj = 0; nj < 4; ++nj) {
      u16x4 pk;
      pk[0] = f2b(acc[mi][nj][0] * inv[nj] * rd.x);
      pk[1] = f2b(acc[mi][nj][1] * inv[nj] * rd.y);
      pk[2] = f2b(acc[mi][nj][2] * inv[nj] * rd.z);
      pk[3] = f2b(acc[mi][nj][3] * inv[nj] * rd.w);
      *(u16x4*)&qs[(nj * 16 + l15) * XTP + w * 32 + mi * 16 + quad * 4] = pk;
    }
  }
  __syncthreads();

  // ---- att GEMM: wave w -> head w; D[vch][tok]; K=32 (one step) ----
  f32x4 aacc[2][4];
  {
    #pragma unroll
    for (int nj = 0; nj < 4; ++nj) {
      bf16x8 bqf = *(const bf16x8*)&qs[(nj * 16 + l15) * XTP + w * 32 + quad * 8];
      #pragma unroll
      for (int mi = 0; mi < 2; ++mi)
        aacc[mi][nj] = mfma16(ac[mi], bqf, (f32x4)0.f);
    }
  }
  // write att over qs (each wave writes exactly the columns only it read)
  #pragma unroll
  for (int mi = 0; mi < 2; ++mi)
    #pragma unroll
    for (int nj = 0; nj < 4; ++nj) {
      u16x4 pk;
      pk[0] = f2b(aacc[mi][nj][0]);
      pk[1] = f2b(aacc[mi][nj][1]);
      pk[2] = f2b(aacc[mi][nj][2]);
      pk[3] = f2b(aacc[mi][nj][3]);
      *(u16x4*)&qs[(nj * 16 + l15) * XTP + w * 32 + mi * 16 + quad * 4] = pk;
    }
  __syncthreads();

  // ---- Wr GEMM ----
  #pragma unroll
  for (int mi = 0; mi < 2; ++mi)
    #pragma unroll
    for (int nj = 0; nj < 4; ++nj) acc[mi][nj] = (f32x4)0.f;
  for (int k0 = 0; k0 < NCH; k0 += 32) {
    bf16x8 af[2], bx[4];
    #pragma unroll
    for (int mi = 0; mi < 2; ++mi)
      af[mi] = *(const bf16x8*)(Wrb + (size_t)(w * 32 + mi * 16 + l15) * NCH + k0 + quad * 8);
    #pragma unroll
    for (int nj = 0; nj < 4; ++nj)
      bx[nj] = *(const bf16x8*)&qs[(nj * 16 + l15) * XTP + k0 + quad * 8];
    #pragma unroll
    for (int mi = 0; mi < 2; ++mi)
      #pragma unroll
      for (int nj = 0; nj < 4; ++nj) acc[mi][nj] = mfma16(af[mi], bx[nj], acc[mi][nj]);
  }
  // bias + residual + transposed float4 store
  #pragma unroll
  for (int mi = 0; mi < 2; ++mi) {
    float4 bb = *(const float4*)(br + w * 32 + mi * 16 + quad * 4);
    #pragma unroll
    for (int nj = 0; nj < 4; ++nj) {
      int tok = nj * 16 + l15;
      u16x4 rx = *(const u16x4*)&xs[tok * XTP + w * 32 + mi * 16 + quad * 4];
      float4 o;
      o.x = acc[mi][nj][0] + bb.x + b2f(rx[0]);
      o.y = acc[mi][nj][1] + bb.y + b2f(rx[1]);
      o.z = acc[mi][nj][2] + bb.z + b2f(rx[2]);
      o.w = acc[mi][nj][3] + bb.w + b2f(rx[3]);
      *(float4*)(out + (((size_t)(b * NTOK + g * TT + tok)) << 8) + w * 32 + mi * 16 + quad * 4) = o;
    }
  }
}

extern "C" void kernel_launch(void* const* d_in, const int* in_sizes, int n_in,
                              void* d_out, int out_size, void* d_ws, size_t ws_size,
                              hipStream_t stream) {
  const float* x  = (const float*)d_in[0];
  const float* Wk = (const float*)d_in[1];
  const float* bk = (const float*)d_in[2];
  const float* Wq = (const float*)d_in[3];
  const float* bq = (const float*)d_in[4];
  const float* Wv = (const float*)d_in[5];
  const float* bv = (const float*)d_in[6];
  const float* Wr = (const float*)d_in[7];
  const float* br = (const float*)d_in[8];
  float* out = (float*)d_out;

  // ws layout (~9.1 MB total)
  char* wsb = (char*)d_ws;
  u16*   ctxPart   = (u16*)wsb;                         // 512*8192 u16  = 8 MB
  float* denomPart = (float*)(wsb + 8388608);           // 512*256 f32   = 0.5 MB
  u16*   ctxT      = (u16*)(wsb + 8912896);             // 32768 u16     = 64 KB
  float* rdenomF   = (float*)(wsb + 8978432);           // 1024 f32      = 4 KB
  u16*   wbf       = (u16*)(wsb + 8982528);             // 4*65536 u16   = 0.5 MB

  hipLaunchKernelGGL(k_prep, dim3(64), dim3(256), 0, stream,
                     Wk, Wq, Wv, Wr, wbf);
  hipLaunchKernelGGL(k_ctx, dim3(512), dim3(512), 0, stream,
                     x, wbf, bk, bv, ctxPart, denomPart);
  hipLaunchKernelGGL(k_red, dim3(132), dim3(256), 0, stream,
                     ctxPart, denomPart, ctxT, rdenomF);
  hipLaunchKernelGGL(k_out, dim3(512), dim3(512), 0, stream,
                     x, wbf, bq, br, ctxT, rdenomF, out);
}

// Round 11
// 131.528 us; speedup vs baseline: 1.2351x; 1.1121x over previous
//
#include <hip/hip_runtime.h>
#include <hip/hip_bf16.h>

#define NTOK 8192
#define NCH  256
#define TT   128         // tokens per tile
#define XTP  264         // stride (u16) for [tok][ch] LDS tiles (16B-aligned rows)
#define EK2  136         // stride (u16) for [ch][tok] LDS tiles (16B-aligned rows)

typedef unsigned short u16;
typedef __attribute__((ext_vector_type(8))) short bf16x8;   // MFMA A/B frag (4 VGPR)
typedef __attribute__((ext_vector_type(4))) float f32x4;    // MFMA C/D frag
typedef __attribute__((ext_vector_type(8))) unsigned short u16x8;
typedef __attribute__((ext_vector_type(4))) unsigned short u16x4;

// Hardware bf16 conversions (RNE, v_cvt path) — r10-verified
__device__ __forceinline__ float b2f(u16 v){
  union { u16 u; __hip_bfloat16 h; } c; c.u = v; return __bfloat162float(c.h);
}
__device__ __forceinline__ u16 f2b(float f){
  union { __hip_bfloat16 h; u16 u; } c; c.h = __float2bfloat16(f); return c.u;
}
__device__ __forceinline__ f32x4 mfma16(bf16x8 a, bf16x8 b, f32x4 c){
  return __builtin_amdgcn_mfma_f32_16x16x32_bf16(a, b, c, 0, 0, 0);
}

// ---------------------------------------------------------------------------
// stage_xtile: global fp32 x tile [256 ch][128 tok] -> bf16 LDS dst [tok][XTP]
// via scratch [ch][EK2]. 512 threads. One internal barrier; caller MUST
// __syncthreads() after return before reading dst or overwriting scratch.
// (TT=128 variant of the r1/r3/r10-verified stage)
// ---------------------------------------------------------------------------
__device__ __forceinline__ void stage_xtile(const float* __restrict__ xb,
                                            u16* scratch, u16* dst, int t)
{
  #pragma unroll
  for (int i = 0; i < 8; ++i) {
    int ch = i * 32 + (t >> 4);          // 32 ch rows per iteration
    int tk = (t & 15) * 8;               // 8 consecutive tokens
    const float* p = xb + (size_t)ch * NTOK + tk;
    float4 v0 = *(const float4*)p;
    float4 v1 = *(const float4*)(p + 4);
    u16x8 pk;
    pk[0]=f2b(v0.x); pk[1]=f2b(v0.y); pk[2]=f2b(v0.z); pk[3]=f2b(v0.w);
    pk[4]=f2b(v1.x); pk[5]=f2b(v1.y); pk[6]=f2b(v1.z); pk[7]=f2b(v1.w);
    *(u16x8*)&scratch[ch * EK2 + tk] = pk;
  }
  __syncthreads();
  // transpose: scratch[ch][tok] -> dst[tok][ch]
  #pragma unroll
  for (int p2 = 0; p2 < 8; ++p2) {
    int idx = p2 * 512 + t;              // 0..4095
    int tok = idx & 127;
    int ch = (idx >> 7) * 8;
    u16x8 o;
    #pragma unroll
    for (int j = 0; j < 8; ++j) o[j] = scratch[(ch + j) * EK2 + tok];
    *(u16x8*)&dst[tok * XTP + ch] = o;
  }
}

// ---------------------------------------------------------------------------
// k_prep: convert Wk/Wq/Wv/Wr fp32 -> bf16 row-major into wbf (64 blocks).
// ---------------------------------------------------------------------------
__global__ __launch_bounds__(256)
void k_prep(const float* __restrict__ Wk, const float* __restrict__ Wq,
            const float* __restrict__ Wv, const float* __restrict__ Wr,
            u16* __restrict__ wbf)
{
  const int t = threadIdx.x, bid = blockIdx.x;
  const int mat = bid >> 4;
  const float* src = (mat == 0) ? Wk : (mat == 1) ? Wq : (mat == 2) ? Wv : Wr;
  u16* dst = wbf + mat * 65536;
  const int base = (bid & 15) * 4096 + t * 16;
  #pragma unroll
  for (int i = 0; i < 4; ++i) {
    float4 v = *(const float4*)(src + base + i * 4);
    u16x4 pk; pk[0]=f2b(v.x); pk[1]=f2b(v.y); pk[2]=f2b(v.z); pk[3]=f2b(v.w);
    *(u16x4*)(dst + base + i * 4) = pk;
  }
}

// ---------------------------------------------------------------------------
// k_ctx: 256 blocks x 512 threads (1 block/CU; 139 KB LDS). Wave w owns
// out-ch slab [32w, 32w+32) == head w. In-LDS x stage; K-GEMM->exp->ekb;
// V-GEMM->vt (aliased over x tile); ctx GEMM (K=128, 4 steps) + denom
// row-sums -> streaming bf16/fp32 partial stores. (r3 structure, TT=128)
// ---------------------------------------------------------------------------
__global__ __launch_bounds__(512, 2)
void k_ctx(const float* __restrict__ x, const u16* __restrict__ wbf,
           const float* __restrict__ bk, const float* __restrict__ bv,
           u16* __restrict__ ctxPart, float* __restrict__ denomPart)
{
  __shared__ u16 bufA[NCH * EK2];   // stage: x tile [128][XTP]; later vt [256][EK2]
  __shared__ u16 ekb[NCH * EK2];    // stage scratch [ch][tok]; later exp(K) [ch][tok]

  const int t = threadIdx.x;
  const int b = blockIdx.x >> 6, g = blockIdx.x & 63;
  const int w = t >> 6, lane = t & 63;
  const int l15 = lane & 15, quad = lane >> 4;
  const u16* Wkb = wbf;
  const u16* Wvb = wbf + 2 * 65536;

  stage_xtile(x + (size_t)b * NCH * NTOK + g * TT, ekb, bufA, t);
  __syncthreads();   // bufA = x tile ready; ekb scratch reads done

  f32x4 acc[2][8];

  // ---- K GEMM: D[och][tok], wave w owns och [32w, 32w+32) ----
  #pragma unroll
  for (int mi = 0; mi < 2; ++mi)
    #pragma unroll
    for (int nj = 0; nj < 8; ++nj) acc[mi][nj] = (f32x4)0.f;
  for (int k0 = 0; k0 < NCH; k0 += 32) {
    bf16x8 af[2], bx[8];
    #pragma unroll
    for (int mi = 0; mi < 2; ++mi)
      af[mi] = *(const bf16x8*)(Wkb + (size_t)(w * 32 + mi * 16 + l15) * NCH + k0 + quad * 8);
    #pragma unroll
    for (int nj = 0; nj < 8; ++nj)
      bx[nj] = *(const bf16x8*)&bufA[(nj * 16 + l15) * XTP + k0 + quad * 8];
    #pragma unroll
    for (int mi = 0; mi < 2; ++mi)
      #pragma unroll
      for (int nj = 0; nj < 8; ++nj) acc[mi][nj] = mfma16(af[mi], bx[nj], acc[mi][nj]);
  }
  // epilogue: bias + exp -> ekb [ch][tok] (wave-exclusive rows)
  #pragma unroll
  for (int mi = 0; mi < 2; ++mi) {
    float4 bb = *(const float4*)(bk + w * 32 + mi * 16 + quad * 4);
    #pragma unroll
    for (int nj = 0; nj < 8; ++nj) {
      int tok = nj * 16 + l15, chb = w * 32 + mi * 16 + quad * 4;
      ekb[(chb + 0) * EK2 + tok] = f2b(__expf(acc[mi][nj][0] + bb.x));
      ekb[(chb + 1) * EK2 + tok] = f2b(__expf(acc[mi][nj][1] + bb.y));
      ekb[(chb + 2) * EK2 + tok] = f2b(__expf(acc[mi][nj][2] + bb.z));
      ekb[(chb + 3) * EK2 + tok] = f2b(__expf(acc[mi][nj][3] + bb.w));
    }
  }

  // ---- V GEMM (re-uses acc regs) ----
  #pragma unroll
  for (int mi = 0; mi < 2; ++mi)
    #pragma unroll
    for (int nj = 0; nj < 8; ++nj) acc[mi][nj] = (f32x4)0.f;
  for (int k0 = 0; k0 < NCH; k0 += 32) {
    bf16x8 af[2], bx[8];
    #pragma unroll
    for (int mi = 0; mi < 2; ++mi)
      af[mi] = *(const bf16x8*)(Wvb + (size_t)(w * 32 + mi * 16 + l15) * NCH + k0 + quad * 8);
    #pragma unroll
    for (int nj = 0; nj < 8; ++nj)
      bx[nj] = *(const bf16x8*)&bufA[(nj * 16 + l15) * XTP + k0 + quad * 8];
    #pragma unroll
    for (int mi = 0; mi < 2; ++mi)
      #pragma unroll
      for (int nj = 0; nj < 8; ++nj) acc[mi][nj] = mfma16(af[mi], bx[nj], acc[mi][nj]);
  }
  __syncthreads();   // all waves done reading x tile; safe to overwrite with vt
  #pragma unroll
  for (int mi = 0; mi < 2; ++mi) {
    float4 bb = *(const float4*)(bv + w * 32 + mi * 16 + quad * 4);
    #pragma unroll
    for (int nj = 0; nj < 8; ++nj) {
      int tok = nj * 16 + l15, chb = w * 32 + mi * 16 + quad * 4;
      bufA[(chb + 0) * EK2 + tok] = f2b(acc[mi][nj][0] + bb.x);
      bufA[(chb + 1) * EK2 + tok] = f2b(acc[mi][nj][1] + bb.y);
      bufA[(chb + 2) * EK2 + tok] = f2b(acc[mi][nj][2] + bb.z);
      bufA[(chb + 3) * EK2 + tok] = f2b(acc[mi][nj][3] + bb.w);
    }
  }
  __syncthreads();

  // ---- ctx GEMM: wave w -> head w. D[kk][vch] = sum_s ek*v (K=128) ----
  f32x4 cacc[2][2];
  #pragma unroll
  for (int mi = 0; mi < 2; ++mi)
    #pragma unroll
    for (int nj = 0; nj < 2; ++nj) cacc[mi][nj] = (f32x4)0.f;
  #pragma unroll
  for (int kc = 0; kc < 4; ++kc) {
    bf16x8 ae[2], bvv[2];
    #pragma unroll
    for (int mi = 0; mi < 2; ++mi)
      ae[mi] = *(const bf16x8*)&ekb[(w * 32 + mi * 16 + l15) * EK2 + kc * 32 + quad * 8];
    #pragma unroll
    for (int nj = 0; nj < 2; ++nj)
      bvv[nj] = *(const bf16x8*)&bufA[(w * 32 + nj * 16 + l15) * EK2 + kc * 32 + quad * 8];
    #pragma unroll
    for (int mi = 0; mi < 2; ++mi)
      #pragma unroll
      for (int nj = 0; nj < 2; ++nj)
        cacc[mi][nj] = mfma16(ae[mi], bvv[nj], cacc[mi][nj]);
  }
  // denominator: threads 0..255 each sum one ek row over 128 tokens
  float dsum = 0.f;
  if (t < 256) {
    #pragma unroll
    for (int s = 0; s < TT; s += 8) {
      u16x8 v = *(const u16x8*)&ekb[t * EK2 + s];
      #pragma unroll
      for (int j = 0; j < 8; ++j) dsum += b2f(v[j]);
    }
  }

  // ---- streaming partial stores (bf16 ctx + fp32 denom, no contention) ----
  u16* cp = ctxPart + ((size_t)(b * 64 + g) << 13);
  #pragma unroll
  for (int mi = 0; mi < 2; ++mi)
    #pragma unroll
    for (int nj = 0; nj < 2; ++nj)
      #pragma unroll
      for (int r = 0; r < 4; ++r) {
        int e = ((w * 32 + mi * 16 + quad * 4 + r) << 5) + nj * 16 + l15;
        cp[e] = f2b(cacc[mi][nj][r]);
      }
  if (t < 256)
    denomPart[(size_t)(b * 64 + g) * 256 + t] = dsum;
}

// ---------------------------------------------------------------------------
// k_red: sum 64 partials -> ctxT bf16 [b][h][vch][kk] (A-operand-ready) and
// rdenomF = 1/denom fp32 [b][256]
// ---------------------------------------------------------------------------
__global__ __launch_bounds__(256)
void k_red(const u16* __restrict__ ctxPart, const float* __restrict__ denomPart,
           u16* __restrict__ ctxT, float* __restrict__ rdenomF)
{
  int i = blockIdx.x * 256 + threadIdx.x;
  if (i < 32768) {
    int b = i >> 13, e = i & 8191;
    const u16* p = ctxPart + ((size_t)(b * 64) << 13) + e;
    float s0 = 0.f, s1 = 0.f, s2 = 0.f, s3 = 0.f;
    #pragma unroll 4
    for (int g = 0; g < 64; g += 4) {
      s0 += b2f(p[(size_t)(g + 0) << 13]);
      s1 += b2f(p[(size_t)(g + 1) << 13]);
      s2 += b2f(p[(size_t)(g + 2) << 13]);
      s3 += b2f(p[(size_t)(g + 3) << 13]);
    }
    float s = (s0 + s1) + (s2 + s3);
    int hh = e >> 10, kk = (e >> 5) & 31, vch = e & 31;
    ctxT[(((b * 8 + hh) * 32 + vch) << 5) + kk] = f2b(s);
  } else if (i < 33792) {
    int j = i - 32768, b = j >> 8, ch = j & 255;
    const float* p = denomPart + (size_t)(b * 64) * 256 + ch;
    float s = 0.f;
    #pragma unroll 8
    for (int g = 0; g < 64; ++g) s += p[(size_t)g << 8];
    rdenomF[j] = 1.0f / s;
  }
}

// ---------------------------------------------------------------------------
// k_out: 256 blocks x 512 threads (1 block/CU; 137 KB LDS). In-LDS x stage;
// Q-GEMM->exp->head softmax * rdenom -> qn LDS [tok][ch]; att GEMM (A=ctxT,
// out aliased over qn, wave-exclusive cols); Wr-GEMM; +bias +bf16 residual;
// coalesced float4 store. (r3 structure, TT=128)
// ---------------------------------------------------------------------------
__global__ __launch_bounds__(512, 2)
void k_out(const float* __restrict__ x, const u16* __restrict__ wbf,
           const float* __restrict__ bq, const float* __restrict__ br,
           const u16* __restrict__ ctxT, const float* __restrict__ rdenomF,
           float* __restrict__ out)
{
  __shared__ u16 xs[TT * XTP];      // x tile [tok][ch]  (128*264 = 67.6 KB)
  __shared__ u16 qs[NCH * EK2];     // stage scratch [256][EK2]; then qn/att [128][XTP]

  const int t = threadIdx.x;
  const int b = blockIdx.x >> 6, g = blockIdx.x & 63;
  const int w = t >> 6, lane = t & 63;
  const int l15 = lane & 15, quad = lane >> 4;
  const u16* Wqb = wbf + 65536;
  const u16* Wrb = wbf + 3 * 65536;

  stage_xtile(x + (size_t)b * NCH * NTOK + g * TT, qs, xs, t);
  __syncthreads();   // xs ready; all qs scratch reads done

  // ---- ctx A-frags from bf16 ctxT (A-operand-ready; L2-hot) ----
  bf16x8 ac[2];
  #pragma unroll
  for (int mi = 0; mi < 2; ++mi)
    ac[mi] = *(const bf16x8*)(ctxT + (((size_t)(b * 8 + w) * 32 + mi * 16 + l15) << 5) + quad * 8);

  f32x4 acc[2][8];
  // ---- Q GEMM: wave w -> och [32w, 32w+32) == head w ----
  #pragma unroll
  for (int mi = 0; mi < 2; ++mi)
    #pragma unroll
    for (int nj = 0; nj < 8; ++nj) acc[mi][nj] = (f32x4)0.f;
  for (int k0 = 0; k0 < NCH; k0 += 32) {
    bf16x8 af[2], bx[8];
    #pragma unroll
    for (int mi = 0; mi < 2; ++mi)
      af[mi] = *(const bf16x8*)(Wqb + (size_t)(w * 32 + mi * 16 + l15) * NCH + k0 + quad * 8);
    #pragma unroll
    for (int nj = 0; nj < 8; ++nj)
      bx[nj] = *(const bf16x8*)&xs[(nj * 16 + l15) * XTP + k0 + quad * 8];
    #pragma unroll
    for (int mi = 0; mi < 2; ++mi)
      #pragma unroll
      for (int nj = 0; nj < 8; ++nj) acc[mi][nj] = mfma16(af[mi], bx[nj], acc[mi][nj]);
  }
  // bias + exp (in place)
  #pragma unroll
  for (int mi = 0; mi < 2; ++mi) {
    float4 bb = *(const float4*)(bq + w * 32 + mi * 16 + quad * 4);
    #pragma unroll
    for (int nj = 0; nj < 8; ++nj) {
      acc[mi][nj][0] = __expf(acc[mi][nj][0] + bb.x);
      acc[mi][nj][1] = __expf(acc[mi][nj][1] + bb.y);
      acc[mi][nj][2] = __expf(acc[mi][nj][2] + bb.z);
      acc[mi][nj][3] = __expf(acc[mi][nj][3] + bb.w);
    }
  }
  // per-(head, token) softmax denom: in-lane sum + quad reduction
  float inv[8];
  #pragma unroll
  for (int nj = 0; nj < 8; ++nj) {
    float s = 0.f;
    #pragma unroll
    for (int mi = 0; mi < 2; ++mi)
      #pragma unroll
      for (int r = 0; r < 4; ++r) s += acc[mi][nj][r];
    s += __shfl_xor(s, 16);
    s += __shfl_xor(s, 32);
    inv[nj] = 1.0f / s;
  }
  // qn = e * inv * rdenom -> qs [tok][ch], packed b64 writes
  #pragma unroll
  for (int mi = 0; mi < 2; ++mi) {
    float4 rd = *(const float4*)(rdenomF + b * 256 + w * 32 + mi * 16 + quad * 4);
    #pragma unroll
    for (int nj = 0; nj < 8; ++nj) {
      u16x4 pk;
      pk[0] = f2b(acc[mi][nj][0] * inv[nj] * rd.x);
      pk[1] = f2b(acc[mi][nj][1] * inv[nj] * rd.y);
      pk[2] = f2b(acc[mi][nj][2] * inv[nj] * rd.z);
      pk[3] = f2b(acc[mi][nj][3] * inv[nj] * rd.w);
      *(u16x4*)&qs[(nj * 16 + l15) * XTP + w * 32 + mi * 16 + quad * 4] = pk;
    }
  }
  __syncthreads();

  // ---- att GEMM: wave w -> head w; D[vch][tok]; K=32 (one step) ----
  f32x4 aacc[2][8];
  {
    #pragma unroll
    for (int nj = 0; nj < 8; ++nj) {
      bf16x8 bqf = *(const bf16x8*)&qs[(nj * 16 + l15) * XTP + w * 32 + quad * 8];
      #pragma unroll
      for (int mi = 0; mi < 2; ++mi)
        aacc[mi][nj] = mfma16(ac[mi], bqf, (f32x4)0.f);
    }
  }
  // write att over qs (each wave writes exactly the columns only it read)
  #pragma unroll
  for (int mi = 0; mi < 2; ++mi)
    #pragma unroll
    for (int nj = 0; nj < 8; ++nj) {
      u16x4 pk;
      pk[0] = f2b(aacc[mi][nj][0]);
      pk[1] = f2b(aacc[mi][nj][1]);
      pk[2] = f2b(aacc[mi][nj][2]);
      pk[3] = f2b(aacc[mi][nj][3]);
      *(u16x4*)&qs[(nj * 16 + l15) * XTP + w * 32 + mi * 16 + quad * 4] = pk;
    }
  __syncthreads();

  // ---- Wr GEMM ----
  #pragma unroll
  for (int mi = 0; mi < 2; ++mi)
    #pragma unroll
    for (int nj = 0; nj < 8; ++nj) acc[mi][nj] = (f32x4)0.f;
  for (int k0 = 0; k0 < NCH; k0 += 32) {
    bf16x8 af[2], bx[8];
    #pragma unroll
    for (int mi = 0; mi < 2; ++mi)
      af[mi] = *(const bf16x8*)(Wrb + (size_t)(w * 32 + mi * 16 + l15) * NCH + k0 + quad * 8);
    #pragma unroll
    for (int nj = 0; nj < 8; ++nj)
      bx[nj] = *(const bf16x8*)&qs[(nj * 16 + l15) * XTP + k0 + quad * 8];
    #pragma unroll
    for (int mi = 0; mi < 2; ++mi)
      #pragma unroll
      for (int nj = 0; nj < 8; ++nj) acc[mi][nj] = mfma16(af[mi], bx[nj], acc[mi][nj]);
  }
  // bias + residual + transposed float4 store
  #pragma unroll
  for (int mi = 0; mi < 2; ++mi) {
    float4 bb = *(const float4*)(br + w * 32 + mi * 16 + quad * 4);
    #pragma unroll
    for (int nj = 0; nj < 8; ++nj) {
      int tok = nj * 16 + l15;
      u16x4 rx = *(const u16x4*)&xs[tok * XTP + w * 32 + mi * 16 + quad * 4];
      float4 o;
      o.x = acc[mi][nj][0] + bb.x + b2f(rx[0]);
      o.y = acc[mi][nj][1] + bb.y + b2f(rx[1]);
      o.z = acc[mi][nj][2] + bb.z + b2f(rx[2]);
      o.w = acc[mi][nj][3] + bb.w + b2f(rx[3]);
      *(float4*)(out + (((size_t)(b * NTOK + g * TT + tok)) << 8) + w * 32 + mi * 16 + quad * 4) = o;
    }
  }
}

extern "C" void kernel_launch(void* const* d_in, const int* in_sizes, int n_in,
                              void* d_out, int out_size, void* d_ws, size_t ws_size,
                              hipStream_t stream) {
  const float* x  = (const float*)d_in[0];
  const float* Wk = (const float*)d_in[1];
  const float* bk = (const float*)d_in[2];
  const float* Wq = (const float*)d_in[3];
  const float* bq = (const float*)d_in[4];
  const float* Wv = (const float*)d_in[5];
  const float* bv = (const float*)d_in[6];
  const float* Wr = (const float*)d_in[7];
  const float* br = (const float*)d_in[8];
  float* out = (float*)d_out;

  // ws layout (~5 MB total)
  char* wsb = (char*)d_ws;
  u16*   ctxPart   = (u16*)wsb;                         // 256*8192 u16  = 4 MB
  float* denomPart = (float*)(wsb + 4194304);           // 256*256 f32   = 256 KB
  u16*   ctxT      = (u16*)(wsb + 4456448);             // 32768 u16     = 64 KB
  float* rdenomF   = (float*)(wsb + 4521984);           // 1024 f32      = 4 KB
  u16*   wbf       = (u16*)(wsb + 4526080);             // 4*65536 u16   = 0.5 MB

  hipLaunchKernelGGL(k_prep, dim3(64), dim3(256), 0, stream,
                     Wk, Wq, Wv, Wr, wbf);
  hipLaunchKernelGGL(k_ctx, dim3(256), dim3(512), 0, stream,
                     x, wbf, bk, bv, ctxPart, denomPart);
  hipLaunchKernelGGL(k_red, dim3(132), dim3(256), 0, stream,
                     ctxPart, denomPart, ctxT, rdenomF);
  hipLaunchKernelGGL(k_out, dim3(256), dim3(512), 0, stream,
                     x, wbf, bq, br, ctxT, rdenomF, out);
}